// Round 1
// baseline (974.215 us; speedup 1.0000x reference)
//
#include <hip/hip_runtime.h>

#define N_NODES 50000
#define N_EDGES 1600000
#define F_IN 8
#define HID 1000
#define R_OUT 100

// ---- float <-> order-preserving uint key (for atomicMax on floats) ----
__device__ __forceinline__ unsigned fkey(float f) {
    unsigned b = __float_as_uint(f);
    return (b & 0x80000000u) ? ~b : (b | 0x80000000u);
}
__device__ __forceinline__ float funkey(unsigned k) {
    unsigned b = (k & 0x80000000u) ? (k & 0x7fffffffu) : ~k;
    return __uint_as_float(b);
}

// ---- workspace zero-init (harness poisons ws with 0xAA every call) ----
__global__ void init_ws(unsigned* __restrict__ p, int n) {
    int i = blockIdx.x * blockDim.x + threadIdx.x;
    if (i < n) p[i] = 0u;
}

// ---- per-edge scatter: mean-dot sum, count, per-feature max ----
__global__ void edge_kernel(const int* __restrict__ ei,
                            const float* __restrict__ X,
                            const float* __restrict__ wl,   // lin_l_w [8]
                            float* __restrict__ sumw,
                            float* __restrict__ cnt,
                            unsigned* __restrict__ maxb) {
    int e = blockIdx.x * blockDim.x + threadIdx.x;
    if (e >= N_EDGES) return;
    int src = ei[e];
    int dst = ei[N_EDGES + e];
    if ((unsigned)src >= N_NODES || (unsigned)dst >= N_NODES) return;  // guard vs dtype surprises
    const float4* X4 = (const float4*)(X + src * F_IN);
    float4 a = X4[0], b = X4[1];
    float f[8] = {a.x, a.y, a.z, a.w, b.x, b.y, b.z, b.w};
    float d = 0.f;
#pragma unroll
    for (int k = 0; k < 8; ++k) d += f[k] * wl[k];
    atomicAdd(&sumw[dst], d);
    atomicAdd(&cnt[dst], 1.0f);
    unsigned* mb = maxb + (size_t)dst * 8;
#pragma unroll
    for (int k = 0; k < 8; ++k) atomicMax(&mb[k], fkey(f[k]));
}

// ---- per-node epilogue: combine mean/max branches -> X_embedding ----
__global__ void node_kernel(const float* __restrict__ X,
                            const float* __restrict__ sumw,
                            const float* __restrict__ cnt,
                            const unsigned* __restrict__ maxb,
                            const float* __restrict__ lin_l_b,
                            const float* __restrict__ lin_r_w,
                            const float* __restrict__ lin_l1_w,
                            const float* __restrict__ lin_l1_b,
                            const float* __restrict__ lin_r1_w,
                            float* __restrict__ xout) {
    int i = blockIdx.x * blockDim.x + threadIdx.x;
    if (i >= N_NODES) return;
    float c = cnt[i];
    float mean_dot = sumw[i] / fmaxf(c, 1.0f);
    const float4* X4 = (const float4*)(X + i * F_IN);
    float4 a = X4[0], b = X4[1];
    float f[8] = {a.x, a.y, a.z, a.w, b.x, b.y, b.z, b.w};
    const uint4* M4 = (const uint4*)(maxb + (size_t)i * 8);
    uint4 m0 = M4[0], m1 = M4[1];
    unsigned mk[8] = {m0.x, m0.y, m0.z, m0.w, m1.x, m1.y, m1.z, m1.w};
    float dr = 0.f, dr1 = 0.f, dmax = 0.f;
    bool nonempty = (c > 0.f);
#pragma unroll
    for (int k = 0; k < 8; ++k) {
        float mx = nonempty ? funkey(mk[k]) : 0.0f;
        dmax += mx * lin_l1_w[k];
        dr   += f[k] * lin_r_w[k];
        dr1  += f[k] * lin_r1_w[k];
    }
    float hm = fmaxf(mean_dot + lin_l_b[0] + dr, 0.f);
    float hx = fmaxf(dmax + lin_l1_b[0] + dr1, 0.f);
    xout[i] = hm + hx;
}

// ---- block-per-row GEMV + bias + ReLU ----
template <int BLOCK>
__global__ void gemv_relu(const float* __restrict__ W,
                          const float* __restrict__ x,
                          const float* __restrict__ bias,
                          float* __restrict__ y, int cols) {
    int row = blockIdx.x;
    const float4* W4 = (const float4*)(W + (size_t)row * cols);
    const float4* x4 = (const float4*)x;
    int n4 = cols >> 2;
    float s = 0.f;
    for (int j = threadIdx.x; j < n4; j += BLOCK) {
        float4 w = W4[j], xx = x4[j];
        s += w.x * xx.x + w.y * xx.y + w.z * xx.z + w.w * xx.w;
    }
#pragma unroll
    for (int off = 32; off > 0; off >>= 1) s += __shfl_down(s, off, 64);
    __shared__ float red[BLOCK / 64];
    int t = threadIdx.x;
    if ((t & 63) == 0) red[t >> 6] = s;
    __syncthreads();
    if (t == 0) {
        float tot = 0.f;
#pragma unroll
        for (int w = 0; w < BLOCK / 64; ++w) tot += red[w];
        y[row] = fmaxf(tot + bias[row], 0.f);
    }
}

extern "C" void kernel_launch(void* const* d_in, const int* in_sizes, int n_in,
                              void* d_out, int out_size, void* d_ws, size_t ws_size,
                              hipStream_t stream) {
    const float* X        = (const float*)d_in[0];
    const int*   ei       = (const int*)d_in[1];
    const float* lin_l_w  = (const float*)d_in[2];
    const float* lin_l_b  = (const float*)d_in[3];
    const float* lin_r_w  = (const float*)d_in[4];
    const float* lin_l1_w = (const float*)d_in[5];
    const float* lin_l1_b = (const float*)d_in[6];
    const float* lin_r1_w = (const float*)d_in[7];
    const float* W0       = (const float*)d_in[8];
    const float* b0       = (const float*)d_in[9];
    const float* W1       = (const float*)d_in[10];
    const float* b1       = (const float*)d_in[11];
    const float* W2       = (const float*)d_in[12];
    const float* b2       = (const float*)d_in[13];

    // workspace layout (4-byte units)
    float*    sumw = (float*)d_ws;                       // [N]
    float*    cnt  = sumw + N_NODES;                     // [N]
    unsigned* maxb = (unsigned*)(cnt + N_NODES);         // [N*8]
    float*    h0   = (float*)(maxb + (size_t)N_NODES*8); // [HID]
    float*    h1   = h0 + HID;                           // [HID]

    float* xemb = (float*)d_out;          // [N] output 0
    float* out2 = xemb + N_NODES;         // [R] output 1

    int zero_words = N_NODES * 10;  // sumw + cnt + maxb
    hipLaunchKernelGGL(init_ws, dim3((zero_words + 255) / 256), dim3(256), 0, stream,
                       (unsigned*)d_ws, zero_words);

    hipLaunchKernelGGL(edge_kernel, dim3((N_EDGES + 255) / 256), dim3(256), 0, stream,
                       ei, X, lin_l_w, sumw, cnt, maxb);

    hipLaunchKernelGGL(node_kernel, dim3((N_NODES + 255) / 256), dim3(256), 0, stream,
                       X, sumw, cnt, maxb, lin_l_b, lin_r_w, lin_l1_w, lin_l1_b, lin_r1_w,
                       xemb);

    hipLaunchKernelGGL(gemv_relu<256>, dim3(HID), dim3(256), 0, stream,
                       W0, xemb, b0, h0, N_NODES);
    hipLaunchKernelGGL(gemv_relu<256>, dim3(HID), dim3(256), 0, stream,
                       W1, h0, b1, h1, HID);
    hipLaunchKernelGGL(gemv_relu<256>, dim3(R_OUT), dim3(256), 0, stream,
                       W2, h1, b2, out2, HID);
}

// Round 2
// 450.412 us; speedup vs baseline: 2.1629x; 2.1629x over previous
//
#include <hip/hip_runtime.h>

#define N_NODES 50000
#define N_EDGES 1600000
#define F_IN 8
#define HID 1000
#define R_OUT 100
#define SCAN_BLOCKS 196   // ceil(50000/256)

// ======================= shared helpers =======================

__device__ __forceinline__ unsigned fkey(float f) {
    unsigned b = __float_as_uint(f);
    return (b & 0x80000000u) ? ~b : (b | 0x80000000u);
}
__device__ __forceinline__ float funkey(unsigned k) {
    unsigned b = (k & 0x80000000u) ? (k & 0x7fffffffu) : ~k;
    return __uint_as_float(b);
}

__global__ void init_ws(unsigned* __restrict__ p, int n) {
    int i = blockIdx.x * blockDim.x + threadIdx.x;
    if (i < n) p[i] = 0u;
}

// ======================= CSR path =======================

// pass 1: degree histogram + per-edge rank within its dst
__global__ void hist_kernel(const int* __restrict__ ei,
                            int* __restrict__ cnt,
                            int* __restrict__ pos) {
    int e = blockIdx.x * blockDim.x + threadIdx.x;
    if (e >= N_EDGES) return;
    int dst = ei[N_EDGES + e];
    pos[e] = atomicAdd(&cnt[dst], 1);
}

// scan stage a: per-block sums of cnt
__global__ void scan_part(const int* __restrict__ cnt, int* __restrict__ part) {
    __shared__ int sc[256];
    int t = threadIdx.x;
    int i = blockIdx.x * 256 + t;
    sc[t] = (i < N_NODES) ? cnt[i] : 0;
    __syncthreads();
    for (int d = 128; d > 0; d >>= 1) {
        if (t < d) sc[t] += sc[t + d];
        __syncthreads();
    }
    if (t == 0) part[blockIdx.x] = sc[0];
}

// scan stage b: exclusive scan of the block sums (single block)
__global__ void scan_mid(const int* __restrict__ part, int* __restrict__ blkoff) {
    __shared__ int sc[SCAN_BLOCKS];
    int t = threadIdx.x;
    if (t < SCAN_BLOCKS) sc[t] = part[t];
    __syncthreads();
    if (t == 0) {
        int run = 0;
        for (int j = 0; j < SCAN_BLOCKS; ++j) { int v = sc[j]; sc[j] = run; run += v; }
    }
    __syncthreads();
    if (t < SCAN_BLOCKS) blkoff[t] = sc[t];
}

// scan stage c: per-block exclusive scan + block offset -> offs
__global__ void scan_final(const int* __restrict__ cnt,
                           const int* __restrict__ blkoff,
                           int* __restrict__ offs) {
    __shared__ int sc[256];
    int t = threadIdx.x;
    int i = blockIdx.x * 256 + t;
    int v = (i < N_NODES) ? cnt[i] : 0;
    sc[t] = v;
    __syncthreads();
    // Hillis-Steele inclusive scan
    for (int d = 1; d < 256; d <<= 1) {
        int x = (t >= d) ? sc[t - d] : 0;
        __syncthreads();
        sc[t] += x;
        __syncthreads();
    }
    if (i < N_NODES) offs[i] = blkoff[blockIdx.x] + sc[t] - v;  // exclusive
}

// pass 2: scatter src indices into CSR buckets (no atomics)
__global__ void scatter_kernel(const int* __restrict__ ei,
                               const int* __restrict__ offs,
                               const int* __restrict__ pos,
                               int* __restrict__ bucket) {
    int e = blockIdx.x * blockDim.x + threadIdx.x;
    if (e >= N_EDGES) return;
    int src = ei[e];
    int dst = ei[N_EDGES + e];
    bucket[offs[dst] + pos[e]] = src;
}

// pass 3: gather + full node epilogue; 16 lanes per node
__global__ void gather_kernel(const int* __restrict__ bucket,
                              const int* __restrict__ offs,
                              const int* __restrict__ cnt,
                              const float* __restrict__ X,
                              const float* __restrict__ lin_l_w,
                              const float* __restrict__ lin_l_b,
                              const float* __restrict__ lin_r_w,
                              const float* __restrict__ lin_l1_w,
                              const float* __restrict__ lin_l1_b,
                              const float* __restrict__ lin_r1_w,
                              float* __restrict__ xemb) {
    int t = blockIdx.x * blockDim.x + threadIdx.x;
    int node = t >> 4;
    int sub = t & 15;
    if (node >= N_NODES) return;
    int base = offs[node];
    int deg = cnt[node];

    float wl[8];
#pragma unroll
    for (int k = 0; k < 8; ++k) wl[k] = lin_l_w[k];

    float sumdot = 0.f;
    float mx[8];
#pragma unroll
    for (int k = 0; k < 8; ++k) mx[k] = -INFINITY;

    for (int j = sub; j < deg; j += 16) {
        int src = bucket[base + j];
        const float4* X4 = (const float4*)(X + src * F_IN);
        float4 a = X4[0], b = X4[1];
        float f[8] = {a.x, a.y, a.z, a.w, b.x, b.y, b.z, b.w};
        float d = 0.f;
#pragma unroll
        for (int k = 0; k < 8; ++k) d += f[k] * wl[k];
        sumdot += d;
#pragma unroll
        for (int k = 0; k < 8; ++k) mx[k] = fmaxf(mx[k], f[k]);
    }
    // reduce across the 16 lanes of this node
#pragma unroll
    for (int m = 8; m >= 1; m >>= 1) {
        sumdot += __shfl_xor(sumdot, m, 16);
#pragma unroll
        for (int k = 0; k < 8; ++k) mx[k] = fmaxf(mx[k], __shfl_xor(mx[k], m, 16));
    }
    if (sub == 0) {
        float c = (float)deg;
        float mean_dot = sumdot / fmaxf(c, 1.0f);
        const float4* X4 = (const float4*)(X + node * F_IN);
        float4 a = X4[0], b = X4[1];
        float f[8] = {a.x, a.y, a.z, a.w, b.x, b.y, b.z, b.w};
        float dr = 0.f, dr1 = 0.f, dmax = 0.f;
        bool nonempty = (deg > 0);
#pragma unroll
        for (int k = 0; k < 8; ++k) {
            float m = nonempty ? mx[k] : 0.0f;
            dmax += m * lin_l1_w[k];
            dr   += f[k] * lin_r_w[k];
            dr1  += f[k] * lin_r1_w[k];
        }
        float hm = fmaxf(mean_dot + lin_l_b[0] + dr, 0.f);
        float hx = fmaxf(dmax + lin_l1_b[0] + dr1, 0.f);
        xemb[node] = hm + hx;
    }
}

// ======================= GEMV =======================

// split-K partial gemv: grid (rows, nchunks); chunk cols must be /4
template <int BLOCK, int NCHUNK>
__global__ void gemv_partial(const float* __restrict__ W,
                             const float* __restrict__ x,
                             float* __restrict__ part, int cols) {
    int row = blockIdx.x;
    int c = blockIdx.y;
    int chunk = cols / NCHUNK;
    const float4* W4 = (const float4*)(W + (size_t)row * cols + (size_t)c * chunk);
    const float4* x4 = (const float4*)(x + c * chunk);
    int n4 = chunk >> 2;
    float s = 0.f;
    for (int j = threadIdx.x; j < n4; j += BLOCK) {
        float4 w = W4[j], xx = x4[j];
        s += w.x * xx.x + w.y * xx.y + w.z * xx.z + w.w * xx.w;
    }
#pragma unroll
    for (int off = 32; off > 0; off >>= 1) s += __shfl_down(s, off, 64);
    __shared__ float red[BLOCK / 64];
    int t = threadIdx.x;
    if ((t & 63) == 0) red[t >> 6] = s;
    __syncthreads();
    if (t == 0) {
        float tot = 0.f;
#pragma unroll
        for (int w = 0; w < BLOCK / 64; ++w) tot += red[w];
        part[row * NCHUNK + c] = tot;
    }
}

template <int NCHUNK>
__global__ void gemv_finalize(const float* __restrict__ part,
                              const float* __restrict__ bias,
                              float* __restrict__ y, int rows) {
    int r = blockIdx.x * blockDim.x + threadIdx.x;
    if (r >= rows) return;
    float s = 0.f;
#pragma unroll
    for (int c = 0; c < NCHUNK; ++c) s += part[r * NCHUNK + c];
    y[r] = fmaxf(s + bias[r], 0.f);
}

template <int BLOCK>
__global__ void gemv_relu(const float* __restrict__ W,
                          const float* __restrict__ x,
                          const float* __restrict__ bias,
                          float* __restrict__ y, int cols) {
    int row = blockIdx.x;
    const float4* W4 = (const float4*)(W + (size_t)row * cols);
    const float4* x4 = (const float4*)x;
    int n4 = cols >> 2;
    float s = 0.f;
    for (int j = threadIdx.x; j < n4; j += BLOCK) {
        float4 w = W4[j], xx = x4[j];
        s += w.x * xx.x + w.y * xx.y + w.z * xx.z + w.w * xx.w;
    }
#pragma unroll
    for (int off = 32; off > 0; off >>= 1) s += __shfl_down(s, off, 64);
    __shared__ float red[BLOCK / 64];
    int t = threadIdx.x;
    if ((t & 63) == 0) red[t >> 6] = s;
    __syncthreads();
    if (t == 0) {
        float tot = 0.f;
#pragma unroll
        for (int w = 0; w < BLOCK / 64; ++w) tot += red[w];
        y[row] = fmaxf(tot + bias[row], 0.f);
    }
}

// ======================= fallback (round-1 atomic path) =======================

__global__ void edge_kernel_fb(const int* __restrict__ ei,
                               const float* __restrict__ X,
                               const float* __restrict__ wl,
                               float* __restrict__ sumw,
                               float* __restrict__ cnt,
                               unsigned* __restrict__ maxb) {
    int e = blockIdx.x * blockDim.x + threadIdx.x;
    if (e >= N_EDGES) return;
    int src = ei[e];
    int dst = ei[N_EDGES + e];
    const float4* X4 = (const float4*)(X + src * F_IN);
    float4 a = X4[0], b = X4[1];
    float f[8] = {a.x, a.y, a.z, a.w, b.x, b.y, b.z, b.w};
    float d = 0.f;
#pragma unroll
    for (int k = 0; k < 8; ++k) d += f[k] * wl[k];
    atomicAdd(&sumw[dst], d);
    atomicAdd(&cnt[dst], 1.0f);
    unsigned* mb = maxb + (size_t)dst * 8;
#pragma unroll
    for (int k = 0; k < 8; ++k) atomicMax(&mb[k], fkey(f[k]));
}

__global__ void node_kernel_fb(const float* __restrict__ X,
                               const float* __restrict__ sumw,
                               const float* __restrict__ cnt,
                               const unsigned* __restrict__ maxb,
                               const float* __restrict__ lin_l_b,
                               const float* __restrict__ lin_r_w,
                               const float* __restrict__ lin_l1_w,
                               const float* __restrict__ lin_l1_b,
                               const float* __restrict__ lin_r1_w,
                               float* __restrict__ xout) {
    int i = blockIdx.x * blockDim.x + threadIdx.x;
    if (i >= N_NODES) return;
    float c = cnt[i];
    float mean_dot = sumw[i] / fmaxf(c, 1.0f);
    const float4* X4 = (const float4*)(X + i * F_IN);
    float4 a = X4[0], b = X4[1];
    float f[8] = {a.x, a.y, a.z, a.w, b.x, b.y, b.z, b.w};
    const uint4* M4 = (const uint4*)(maxb + (size_t)i * 8);
    uint4 m0 = M4[0], m1 = M4[1];
    unsigned mk[8] = {m0.x, m0.y, m0.z, m0.w, m1.x, m1.y, m1.z, m1.w};
    float dr = 0.f, dr1 = 0.f, dmax = 0.f;
    bool nonempty = (c > 0.f);
#pragma unroll
    for (int k = 0; k < 8; ++k) {
        float mxv = nonempty ? funkey(mk[k]) : 0.0f;
        dmax += mxv * lin_l1_w[k];
        dr   += f[k] * lin_r_w[k];
        dr1  += f[k] * lin_r1_w[k];
    }
    float hm = fmaxf(mean_dot + lin_l_b[0] + dr, 0.f);
    float hx = fmaxf(dmax + lin_l1_b[0] + dr1, 0.f);
    xout[i] = hm + hx;
}

// ======================= launch =======================

extern "C" void kernel_launch(void* const* d_in, const int* in_sizes, int n_in,
                              void* d_out, int out_size, void* d_ws, size_t ws_size,
                              hipStream_t stream) {
    const float* X        = (const float*)d_in[0];
    const int*   ei       = (const int*)d_in[1];
    const float* lin_l_w  = (const float*)d_in[2];
    const float* lin_l_b  = (const float*)d_in[3];
    const float* lin_r_w  = (const float*)d_in[4];
    const float* lin_l1_w = (const float*)d_in[5];
    const float* lin_l1_b = (const float*)d_in[6];
    const float* lin_r1_w = (const float*)d_in[7];
    const float* W0       = (const float*)d_in[8];
    const float* b0       = (const float*)d_in[9];
    const float* W1       = (const float*)d_in[10];
    const float* b1       = (const float*)d_in[11];
    const float* W2       = (const float*)d_in[12];
    const float* b2       = (const float*)d_in[13];

    float* xemb = (float*)d_out;
    float* out2 = xemb + N_NODES;

    // CSR-path workspace layout (4-byte words)
    const size_t need_words = (size_t)N_NODES * 2 + (size_t)N_EDGES * 2
                              + 256 + 256 + HID * 4 + HID + HID;
    if (ws_size >= need_words * 4) {
        int*   cnt    = (int*)d_ws;                 // [N]
        int*   offs   = cnt + N_NODES;              // [N]
        int*   pos    = offs + N_NODES;             // [E]
        int*   bucket = pos + N_EDGES;              // [E]
        int*   part   = bucket + N_EDGES;           // [256]
        int*   blkoff = part + 256;                 // [256]
        float* part0  = (float*)(blkoff + 256);     // [HID*4]
        float* h0     = part0 + HID * 4;            // [HID]
        float* h1     = h0 + HID;                   // [HID]

        hipLaunchKernelGGL(init_ws, dim3((N_NODES + 255) / 256), dim3(256), 0, stream,
                           (unsigned*)cnt, N_NODES);
        hipLaunchKernelGGL(hist_kernel, dim3((N_EDGES + 255) / 256), dim3(256), 0, stream,
                           ei, cnt, pos);
        hipLaunchKernelGGL(scan_part, dim3(SCAN_BLOCKS), dim3(256), 0, stream, cnt, part);
        hipLaunchKernelGGL(scan_mid, dim3(1), dim3(256), 0, stream, part, blkoff);
        hipLaunchKernelGGL(scan_final, dim3(SCAN_BLOCKS), dim3(256), 0, stream,
                           cnt, blkoff, offs);
        hipLaunchKernelGGL(scatter_kernel, dim3((N_EDGES + 255) / 256), dim3(256), 0, stream,
                           ei, offs, pos, bucket);
        hipLaunchKernelGGL(gather_kernel, dim3((N_NODES * 16) / 256), dim3(256), 0, stream,
                           bucket, offs, cnt, X, lin_l_w, lin_l_b, lin_r_w,
                           lin_l1_w, lin_l1_b, lin_r1_w, xemb);

        hipLaunchKernelGGL((gemv_partial<256, 4>), dim3(HID, 4), dim3(256), 0, stream,
                           W0, xemb, part0, N_NODES);
        hipLaunchKernelGGL(gemv_finalize<4>, dim3((HID + 255) / 256), dim3(256), 0, stream,
                           part0, b0, h0, HID);
        hipLaunchKernelGGL(gemv_relu<256>, dim3(HID), dim3(256), 0, stream,
                           W1, h0, b1, h1, HID);
        hipLaunchKernelGGL(gemv_relu<256>, dim3(R_OUT), dim3(256), 0, stream,
                           W2, h1, b2, out2, HID);
    } else {
        // fallback: round-1 atomic path (needs ~2 MB)
        float*    sumw = (float*)d_ws;
        float*    cntf = sumw + N_NODES;
        unsigned* maxb = (unsigned*)(cntf + N_NODES);
        float*    h0   = (float*)(maxb + (size_t)N_NODES * 8);
        float*    h1   = h0 + HID;

        int zero_words = N_NODES * 10;
        hipLaunchKernelGGL(init_ws, dim3((zero_words + 255) / 256), dim3(256), 0, stream,
                           (unsigned*)d_ws, zero_words);
        hipLaunchKernelGGL(edge_kernel_fb, dim3((N_EDGES + 255) / 256), dim3(256), 0, stream,
                           ei, X, lin_l_w, sumw, cntf, maxb);
        hipLaunchKernelGGL(node_kernel_fb, dim3((N_NODES + 255) / 256), dim3(256), 0, stream,
                           X, sumw, cntf, maxb, lin_l_b, lin_r_w, lin_l1_w, lin_l1_b,
                           lin_r1_w, xemb);
        hipLaunchKernelGGL(gemv_relu<256>, dim3(HID), dim3(256), 0, stream,
                           W0, xemb, b0, h0, N_NODES);
        hipLaunchKernelGGL(gemv_relu<256>, dim3(HID), dim3(256), 0, stream,
                           W1, h0, b1, h1, HID);
        hipLaunchKernelGGL(gemv_relu<256>, dim3(R_OUT), dim3(256), 0, stream,
                           W2, h1, b2, out2, HID);
    }
}